// Round 5
// baseline (1125.082 us; speedup 1.0000x reference)
//
#include <hip/hip_runtime.h>
#include <math.h>
#include <stdint.h>

#define H 2048
#define B 1024
#define NB 12

#define NBLK 256
#define NTHR 512
#define ROWS_PER_BLK 32   // 8192 rows / 256 blocks
#define CHUNKS 256        // uint4 (8 int16) chunks per 2048-col row
#define NSTEP 23

// ws layout (bytes):
//   [0, 32MB)            Wih int16 (8192 x 2048)
//   [32MB, 64MB)         Whh int16
//   [64MB, +32KB)        sih (8192 f)
//   [.., +32KB)          shh (8192 f)
//   [.., +32KB)          gates buf 0 (8192 f)
//   [.., +32KB)          gates buf 1 (8192 f)
//   [.., +4KB)           barrier counter (int) + state for fallback
#define W16_BYTES   (8192ull * 2048ull * 2ull)              // 32 MB each
#define SOFF_BYTES  (2ull * W16_BYTES)                      // 64 MB
#define GOFF_BYTES  (SOFF_BYTES + 2ull * 8192ull * 4ull)    // + 64 KB
#define COFF_BYTES  (GOFF_BYTES + 2ull * 8192ull * 4ull)    // + 64 KB
#define WS_NEED     (COFF_BYTES + 4096ull)

// ---------------- int16 quantization: one wave per row -------------------
__global__ __launch_bounds__(256) void quant_i16_kernel(
    const float* __restrict__ src, uint4* __restrict__ dst,
    float* __restrict__ scales) {
    const int wave = threadIdx.x >> 6;
    const int lane = threadIdx.x & 63;
    const int row = blockIdx.x * 4 + wave;

    const float4* __restrict__ s4 = (const float4*)(src + (size_t)row * H);
    float4 va[4], vb[4];
    float m = 0.f;
#pragma unroll
    for (int k = 0; k < 4; ++k) {
        const int ci = k * 64 + lane;
        va[k] = s4[2 * ci];
        vb[k] = s4[2 * ci + 1];
        m = fmaxf(m, fmaxf(fmaxf(fabsf(va[k].x), fabsf(va[k].y)),
                           fmaxf(fabsf(va[k].z), fabsf(va[k].w))));
        m = fmaxf(m, fmaxf(fmaxf(fabsf(vb[k].x), fabsf(vb[k].y)),
                           fmaxf(fabsf(vb[k].z), fabsf(vb[k].w))));
    }
#pragma unroll
    for (int off = 32; off > 0; off >>= 1)
        m = fmaxf(m, __shfl_xor(m, off, 64));
    const float inv = (m > 0.f) ? 32767.f / m : 0.f;

    uint4* __restrict__ drow = dst + (size_t)row * CHUNKS;
#pragma unroll
    for (int k = 0; k < 4; ++k) {
        const int ci = k * 64 + lane;
        int q0 = (int)rintf(va[k].x * inv), q1 = (int)rintf(va[k].y * inv);
        int q2 = (int)rintf(va[k].z * inv), q3 = (int)rintf(va[k].w * inv);
        int q4 = (int)rintf(vb[k].x * inv), q5 = (int)rintf(vb[k].y * inv);
        int q6 = (int)rintf(vb[k].z * inv), q7 = (int)rintf(vb[k].w * inv);
        uint4 o;
        o.x = ((uint32_t)q0 & 0xffffu) | ((uint32_t)q1 << 16);
        o.y = ((uint32_t)q2 & 0xffffu) | ((uint32_t)q3 << 16);
        o.z = ((uint32_t)q4 & 0xffffu) | ((uint32_t)q5 << 16);
        o.w = ((uint32_t)q6 & 0xffffu) | ((uint32_t)q7 << 16);
        drow[ci] = o;
    }
    if (lane == 0) scales[row] = (m > 0.f) ? m / 32767.f : 0.f;
}

// ---------------- persistent LSTM kernel ---------------------------------
__device__ __forceinline__ float cvt_lo(uint32_t u) {
    return (float)((int)(u << 16) >> 16);
}
__device__ __forceinline__ float cvt_hi(uint32_t u) {
    return (float)((int)u >> 16);
}
__device__ __forceinline__ float i16dot(uint4 w, float4 a, float4 b) {
    return cvt_lo(w.x) * a.x + cvt_hi(w.x) * a.y +
           cvt_lo(w.y) * a.z + cvt_hi(w.y) * a.w +
           cvt_lo(w.z) * b.x + cvt_hi(w.z) * b.y +
           cvt_lo(w.w) * b.z + cvt_hi(w.w) * b.w;
}

__device__ __forceinline__ void grid_barrier(int* ctr, int target) {
    __syncthreads();  // drains this block's stores (vmcnt0 before s_barrier)
    if (threadIdx.x == 0) {
        __threadfence();  // agent release: write back dirty L2
        __hip_atomic_fetch_add(ctr, 1, __ATOMIC_RELEASE,
                               __HIP_MEMORY_SCOPE_AGENT);
        while (__hip_atomic_load(ctr, __ATOMIC_ACQUIRE,
                                 __HIP_MEMORY_SCOPE_AGENT) < target)
            __builtin_amdgcn_s_sleep(2);
        __threadfence();  // agent acquire: invalidate caches
    }
    __syncthreads();
}

__global__ __launch_bounds__(NTHR, 2) void lstm_persistent(
    const uint4* __restrict__ Wih, const uint4* __restrict__ Whh,
    const float* __restrict__ sih, const float* __restrict__ shh,
    const float* __restrict__ bih, const float* __restrict__ bhh,
    const float* __restrict__ enc_act, const float* __restrict__ enc_block,
    const float* __restrict__ dec_act, const float* __restrict__ dec_block,
    float* __restrict__ g0, float* __restrict__ g1,
    int* __restrict__ ctr, float* __restrict__ out) {
    __shared__ float h_s[H];
    __shared__ float c_s[H];
    __shared__ float x_s[H];
    __shared__ float logits_s[16];

    const int tid = threadIdx.x;
    const int wv = tid >> 6;
    const int lane = tid & 63;
    const int bid = blockIdx.x;

    for (int j = tid; j < H; j += NTHR) {
        h_s[j] = 0.f; c_s[j] = 0.f; x_s[j] = 0.f;
    }
    __syncthreads();

    int idx = 0;
    for (int t = 0; t < NSTEP; ++t) {
        float* gates = (t & 1) ? g1 : g0;

        // ---- matvec: this wave computes 4 rows -------------------------
        const int row0 = bid * ROWS_PER_BLK + wv * 4;
        float ai[4] = {0.f, 0.f, 0.f, 0.f};
        float ah[4] = {0.f, 0.f, 0.f, 0.f};
#pragma unroll
        for (int cc = 0; cc < 4; ++cc) {
            const int ci = cc * 64 + lane;
            const float4 xa = ((const float4*)x_s)[2 * ci];
            const float4 xb = ((const float4*)x_s)[2 * ci + 1];
            const float4 ha = ((const float4*)h_s)[2 * ci];
            const float4 hb = ((const float4*)h_s)[2 * ci + 1];
#pragma unroll
            for (int r = 0; r < 4; ++r) {
                uint4 w = Wih[(size_t)(row0 + r) * CHUNKS + ci];
                ai[r] += i16dot(w, xa, xb);
            }
#pragma unroll
            for (int r = 0; r < 4; ++r) {
                uint4 w = Whh[(size_t)(row0 + r) * CHUNKS + ci];
                ah[r] += i16dot(w, ha, hb);
            }
        }
#pragma unroll
        for (int off = 32; off > 0; off >>= 1) {
#pragma unroll
            for (int r = 0; r < 4; ++r) {
                ai[r] += __shfl_down(ai[r], off, 64);
                ah[r] += __shfl_down(ah[r], off, 64);
            }
        }
        if (lane == 0) {
#pragma unroll
            for (int r = 0; r < 4; ++r) {
                const int row = row0 + r;
                gates[row] = ai[r] * sih[row] + ah[r] * shh[row] +
                             bih[row] + bhh[row];
            }
        }

        grid_barrier(ctr, NBLK * (t + 1));

        // ---- redundant update: thread owns elements 4*tid..4*tid+3 -----
        {
            const float4 gi = ((const float4*)gates)[tid];
            const float4 gf = ((const float4*)gates)[tid + 512];
            const float4 gg = ((const float4*)gates)[tid + 1024];
            const float4 go = ((const float4*)gates)[tid + 1536];
            float4 c = ((float4*)c_s)[tid];
            float4 cn, hn;
            {
                float si = 1.f / (1.f + expf(-gi.x));
                float sf = 1.f / (1.f + expf(-gf.x));
                float so = 1.f / (1.f + expf(-go.x));
                cn.x = sf * c.x + si * tanhf(gg.x);
                hn.x = so * tanhf(cn.x);
            }
            {
                float si = 1.f / (1.f + expf(-gi.y));
                float sf = 1.f / (1.f + expf(-gf.y));
                float so = 1.f / (1.f + expf(-go.y));
                cn.y = sf * c.y + si * tanhf(gg.y);
                hn.y = so * tanhf(cn.y);
            }
            {
                float si = 1.f / (1.f + expf(-gi.z));
                float sf = 1.f / (1.f + expf(-gf.z));
                float so = 1.f / (1.f + expf(-go.z));
                cn.z = sf * c.z + si * tanhf(gg.z);
                hn.z = so * tanhf(cn.z);
            }
            {
                float si = 1.f / (1.f + expf(-gi.w));
                float sf = 1.f / (1.f + expf(-gf.w));
                float so = 1.f / (1.f + expf(-go.w));
                cn.w = sf * c.w + si * tanhf(gg.w);
                hn.w = so * tanhf(cn.w);
            }
            ((float4*)c_s)[tid] = cn;
            ((float4*)h_s)[tid] = hn;
        }
        __syncthreads();

        // ---- decode (redundant per block): wave wv does classes wv,wv+8
        int nclass;
        const float* dec;
        if (t == 0) { nclass = 4; dec = dec_act; }
        else if (t & 1) {
            const int b2 = (t + 1) >> 1;
            nclass = b2;
            dec = dec_block + (size_t)(b2 - 1) * (NB - 1) * H;
        } else {
            const int b2 = t >> 1;
            nclass = 4;
            dec = dec_act + (size_t)b2 * 4 * H;
        }
        for (int cl = wv; cl < nclass; cl += 8) {
            const float4* dr = (const float4*)(dec + (size_t)cl * H);
            float p = 0.f;
#pragma unroll
            for (int k = 0; k < 8; ++k) {
                float4 d = dr[k * 64 + lane];
                float4 hh = ((const float4*)h_s)[k * 64 + lane];
                p += d.x * hh.x + d.y * hh.y + d.z * hh.z + d.w * hh.w;
            }
#pragma unroll
            for (int off = 32; off > 0; off >>= 1)
                p += __shfl_down(p, off, 64);
            if (lane == 0) logits_s[cl] = p;
        }
        __syncthreads();

        {
            float best = logits_s[0];
            int bi = 0;
            for (int cl = 1; cl < nclass; ++cl)
                if (logits_s[cl] > best) { best = logits_s[cl]; bi = cl; }
            idx = bi;
        }

        // ---- gather next x = enc[idx] ----------------------------------
        const float* encp = nullptr;
        if (t == 0) encp = enc_act;
        else if (t & 1) {
            const int b2 = (t + 1) >> 1;
            encp = enc_block + (size_t)(b2 - 1) * (NB - 1) * H;
        } else if (t < NSTEP - 1) {
            const int b2 = t >> 1;
            encp = enc_act + (size_t)b2 * 4 * H;
        }
        if (encp) {
            const float4* er = (const float4*)(encp + (size_t)idx * H);
            ((float4*)x_s)[tid] = er[tid];
        }
        __syncthreads();
    }

    // ---- final output ---------------------------------------------------
    if (bid == 0)
        for (int j = tid; j < B; j += NTHR) out[j] = (float)idx;
    float* oh = out + B;
    float* oc = out + B + (size_t)B * H;
#pragma unroll
    for (int rr = 0; rr < 4; ++rr) {
        const int orow = bid * 4 + rr;
        for (int j = tid; j < H / 4; j += NTHR) {
            ((float4*)(oh + (size_t)orow * H))[j] = ((const float4*)h_s)[j];
            ((float4*)(oc + (size_t)orow * H))[j] = ((const float4*)c_s)[j];
        }
    }
}

// ---------------- fp32 fallback path (tiny ws) ---------------------------
__global__ __launch_bounds__(256) void zero_c_kernel(float* __restrict__ cv) {
    int j = blockIdx.x * 256 + threadIdx.x;
    if (j < H) cv[j] = 0.f;
}

__global__ __launch_bounds__(256) void bias_gates_kernel(
    const float* __restrict__ bih, const float* __restrict__ bhh,
    float* __restrict__ gates) {
    int j = blockIdx.x * 256 + threadIdx.x;
    if (j < 4 * H) gates[j] = bih[j] + bhh[j];
}

__global__ __launch_bounds__(256) void gates_kernel(
    const float* __restrict__ Wih, const float* __restrict__ Whh,
    const float* __restrict__ bih, const float* __restrict__ bhh,
    const float* __restrict__ x, const float* __restrict__ h,
    float* __restrict__ gates) {
    const int wave = threadIdx.x >> 6;
    const int lane = threadIdx.x & 63;
    const int row = blockIdx.x * 4 + wave;

    const float4* __restrict__ Wi4 = (const float4*)(Wih + (size_t)row * H);
    const float4* __restrict__ Wh4 = (const float4*)(Whh + (size_t)row * H);
    const float4* __restrict__ x4 = (const float4*)x;
    const float4* __restrict__ h4 = (const float4*)h;

    float acc = 0.f;
#pragma unroll
    for (int k = 0; k < H / 256; ++k) {
        int j = k * 64 + lane;
        float4 w = Wi4[j];
        float4 v = x4[j];
        acc += w.x * v.x + w.y * v.y + w.z * v.z + w.w * v.w;
    }
#pragma unroll
    for (int k = 0; k < H / 256; ++k) {
        int j = k * 64 + lane;
        float4 w = Wh4[j];
        float4 v = h4[j];
        acc += w.x * v.x + w.y * v.y + w.z * v.z + w.w * v.w;
    }
    for (int off = 32; off > 0; off >>= 1) acc += __shfl_down(acc, off, 64);
    if (lane == 0) gates[row] = acc + bih[row] + bhh[row];
}

__global__ __launch_bounds__(256) void update_kernel(
    const float* __restrict__ gates,
    float* __restrict__ xv, float* __restrict__ hv, float* __restrict__ cv,
    const float* __restrict__ dec, int nclass,
    const float* __restrict__ enc, int* __restrict__ idx_ptr) {
    const int t = threadIdx.x;
    __shared__ float red[256];
    __shared__ float logits[16];
    __shared__ int sidx;

    float hl[8];
#pragma unroll
    for (int k = 0; k < 8; ++k) {
        int j = k * 256 + t;
        float ig = gates[j];
        float fg = gates[H + j];
        float gg = gates[2 * H + j];
        float og = gates[3 * H + j];
        float si = 1.f / (1.f + expf(-ig));
        float sf = 1.f / (1.f + expf(-fg));
        float so = 1.f / (1.f + expf(-og));
        float tg = tanhf(gg);
        float c2 = sf * cv[j] + si * tg;
        float h2 = so * tanhf(c2);
        cv[j] = c2;
        hv[j] = h2;
        hl[k] = h2;
    }
    __syncthreads();

    for (int cl = 0; cl < nclass; ++cl) {
        const float* dr = dec + (size_t)cl * H;
        float p = 0.f;
#pragma unroll
        for (int k = 0; k < 8; ++k) p += hl[k] * dr[k * 256 + t];
        red[t] = p;
        __syncthreads();
        for (int s = 128; s > 0; s >>= 1) {
            if (t < s) red[t] += red[t + s];
            __syncthreads();
        }
        if (t == 0) logits[cl] = red[0];
        __syncthreads();
    }

    if (t == 0) {
        float best = logits[0];
        int bi = 0;
        for (int cl = 1; cl < nclass; ++cl)
            if (logits[cl] > best) { best = logits[cl]; bi = cl; }
        sidx = bi;
        *idx_ptr = bi;
    }
    __syncthreads();

    if (enc != nullptr) {
        const float* er = enc + (size_t)sidx * H;
#pragma unroll
        for (int k = 0; k < 8; ++k) {
            int j = k * 256 + t;
            xv[j] = er[j];
        }
    }
}

__global__ __launch_bounds__(256) void final_kernel(
    const float* __restrict__ hv, const float* __restrict__ cv,
    const int* __restrict__ idx_ptr, float* __restrict__ out) {
    const int tid = blockIdx.x * 256 + threadIdx.x;
    const int col = tid & (H / 4 - 1);
    const float4 h4 = ((const float4*)hv)[col];
    const float4 c4 = ((const float4*)cv)[col];
    ((float4*)(out + B))[tid] = h4;
    ((float4*)(out + B + (size_t)B * H))[tid] = c4;
    if (tid < B) out[tid] = (float)(*idx_ptr);
}

extern "C" void kernel_launch(void* const* d_in, const int* in_sizes, int n_in,
                              void* d_out, int out_size, void* d_ws, size_t ws_size,
                              hipStream_t stream) {
    const float* W_ih      = (const float*)d_in[1];
    const float* W_hh      = (const float*)d_in[2];
    const float* b_ih      = (const float*)d_in[3];
    const float* b_hh      = (const float*)d_in[4];
    const float* enc_act   = (const float*)d_in[5];  // (NB-1, 4, H)
    const float* enc_block = (const float*)d_in[6];  // (NB-1, NB-1, H)
    const float* dec_act   = (const float*)d_in[7];  // (NB, 4, H)
    const float* dec_block = (const float*)d_in[8];  // (NB-1, NB-1, H)
    float* out = (float*)d_out;

    if (ws_size >= WS_NEED) {
        uint4* Wih16 = (uint4*)d_ws;
        uint4* Whh16 = (uint4*)((char*)d_ws + W16_BYTES);
        float* sih = (float*)((char*)d_ws + SOFF_BYTES);
        float* shh = sih + 8192;
        float* g0 = (float*)((char*)d_ws + GOFF_BYTES);
        float* g1 = g0 + 8192;
        int* ctr = (int*)((char*)d_ws + COFF_BYTES);

        quant_i16_kernel<<<2048, 256, 0, stream>>>(W_ih, Wih16, sih);
        quant_i16_kernel<<<2048, 256, 0, stream>>>(W_hh, Whh16, shh);
        hipMemsetAsync(ctr, 0, sizeof(int), stream);

        lstm_persistent<<<NBLK, NTHR, 0, stream>>>(
            Wih16, Whh16, sih, shh, b_ih, b_hh,
            enc_act, enc_block, dec_act, dec_block, g0, g1, ctr, out);
        return;
    }

    // -------- fallback: fp32 multi-kernel path --------
    float* state = (float*)d_ws;
    float* xv    = state;
    float* hv    = state + H;
    float* cv    = state + 2 * H;
    float* gates = state + 3 * H;
    int*   idxp  = (int*)(state + 7 * H);

    zero_c_kernel<<<8, 256, 0, stream>>>(cv);
    bias_gates_kernel<<<32, 256, 0, stream>>>(b_ih, b_hh, gates);
    update_kernel<<<1, 256, 0, stream>>>(gates, xv, hv, cv,
                                         dec_act, 4, enc_act, idxp);

    for (int bid = 1; bid < NB; ++bid) {
        gates_kernel<<<2048, 256, 0, stream>>>(W_ih, W_hh, b_ih, b_hh,
                                               xv, hv, gates);
        update_kernel<<<1, 256, 0, stream>>>(
            gates, xv, hv, cv,
            dec_block + (size_t)(bid - 1) * (NB - 1) * H, bid,
            enc_block + (size_t)(bid - 1) * (NB - 1) * H, idxp);

        gates_kernel<<<2048, 256, 0, stream>>>(W_ih, W_hh, b_ih, b_hh,
                                               xv, hv, gates);
        update_kernel<<<1, 256, 0, stream>>>(
            gates, xv, hv, cv,
            dec_act + (size_t)bid * 4 * H, 4,
            (bid < NB - 1) ? (enc_act + (size_t)bid * 4 * H) : nullptr, idxp);
    }

    final_kernel<<<2048, 256, 0, stream>>>(hv, cv, idxp, out);
}

// Round 6
// 759.787 us; speedup vs baseline: 1.4808x; 1.4808x over previous
//
#include <hip/hip_runtime.h>
#include <math.h>
#include <stdint.h>

#define H 2048
#define B 1024
#define NB 12
#define NSTEP 23

#define NBLK 256
#define NTHR 512

#define NEMB 176      // 166 used (44 act + 121 block + zero), padded to 176
#define ZSLOT 165

// ---------------- ws layout (bytes) ----------------
#define OFF_WHH  0ull
#define SZ_WHH   (8192ull * 2048ull * 2ull)            // 32 MB int16
#define OFF_SHH  (OFF_WHH + SZ_WHH)
#define SZ_SHH   (8192ull * 4ull)
#define OFF_E    (OFF_SHH + SZ_SHH)
#define SZ_E     ((size_t)NEMB * H * 2ull)             // bf16
#define OFF_PRE  (OFF_E + SZ_E)
#define SZ_PRE   ((size_t)NEMB * 8192ull * 4ull)
#define OFF_H0   (OFF_PRE + SZ_PRE)
#define OFF_H1   (OFF_H0 + 8192ull)
#define OFF_C    (OFF_H1 + 8192ull)
#define OFF_P0   (OFF_C + 8192ull)
#define OFF_P1   (OFF_P0 + 16384ull)
#define OFF_ARR  (OFF_P1 + 16384ull)
#define WS_NEED  (OFF_ARR + 4096ull)

typedef __attribute__((ext_vector_type(8))) short v8s;
typedef __attribute__((ext_vector_type(4))) float v4f;

__device__ __forceinline__ uint32_t bf16rne(float f) {
    uint32_t u = __float_as_uint(f);
    return (u + 0x7fffu + ((u >> 16) & 1u)) >> 16;
}
__device__ __forceinline__ float sigm(float x) { return 1.f / (1.f + expf(-x)); }

// ---------------- gather embeddings -> bf16 E[NEMB][H] -------------------
__global__ __launch_bounds__(256) void build_e_kernel(
    const float* __restrict__ enc_act, const float* __restrict__ enc_block,
    uint32_t* __restrict__ E) {   // 2 bf16 per u32, row = H/2 u32
    const int r = blockIdx.x;
    const int t = threadIdx.x;    // each thread: 8 cols -> one uint4
    uint4 o = {0, 0, 0, 0};
    const float* src = nullptr;
    if (r < 44) src = enc_act + (size_t)r * H;
    else if (r < 165) src = enc_block + (size_t)(r - 44) * H;
    if (src) {
        float4 a = ((const float4*)src)[2 * t];
        float4 b = ((const float4*)src)[2 * t + 1];
        o.x = bf16rne(a.x) | (bf16rne(a.y) << 16);
        o.y = bf16rne(a.z) | (bf16rne(a.w) << 16);
        o.z = bf16rne(b.x) | (bf16rne(b.y) << 16);
        o.w = bf16rne(b.z) | (bf16rne(b.w) << 16);
    }
    ((uint4*)(E + (size_t)r * (H / 2)))[t] = o;
}

// ---------------- PRE = E @ W_ih^T + (b_ih+b_hh), bf16 MFMA --------------
// A = E [M=176][K], B = W_ih rows [N=8192][K]; D[m][n] -> PRE[m*8192+n]
// mfma_f32_16x16x32_bf16 layouts (guide-verified):
//   A: m=lane&15, k=quad*8+j ; B: n=lane&15, k=quad*8+j
//   D: m=quad*4+reg, n=lane&15
__global__ __launch_bounds__(128) void pre_mfma_kernel(
    const float* __restrict__ W,       // W_ih [8192][2048] fp32
    const uint16_t* __restrict__ E,    // [NEMB][2048] bf16
    const float* __restrict__ bih, const float* __restrict__ bhh,
    float* __restrict__ PRE) {
    const int wv = threadIdx.x >> 6;
    const int lane = threadIdx.x & 63;
    const int tN = blockIdx.x * 2 + wv;          // 0..511
    const int l16 = lane & 15;
    const int quad = lane >> 4;
    const int row = tN * 16 + l16;               // W row = N index
    const float* wp = W + (size_t)row * H;

    v4f acc[11];
#pragma unroll
    for (int m = 0; m < 11; ++m) acc[m] = (v4f){0.f, 0.f, 0.f, 0.f};

    for (int ks = 0; ks < 64; ++ks) {
        const int ko = ks * 32 + quad * 8;
        float4 wa = *(const float4*)(wp + ko);
        float4 wb = *(const float4*)(wp + ko + 4);
        v8s bfrag;
        bfrag[0] = (short)bf16rne(wa.x); bfrag[1] = (short)bf16rne(wa.y);
        bfrag[2] = (short)bf16rne(wa.z); bfrag[3] = (short)bf16rne(wa.w);
        bfrag[4] = (short)bf16rne(wb.x); bfrag[5] = (short)bf16rne(wb.y);
        bfrag[6] = (short)bf16rne(wb.z); bfrag[7] = (short)bf16rne(wb.w);
#pragma unroll
        for (int m = 0; m < 11; ++m) {
            v8s afrag = *(const v8s*)(E + (size_t)(m * 16 + l16) * H + ko);
            acc[m] = __builtin_amdgcn_mfma_f32_16x16x32_bf16(afrag, bfrag,
                                                             acc[m], 0, 0, 0);
        }
    }
    const float bias = bih[row] + bhh[row];
#pragma unroll
    for (int m = 0; m < 11; ++m)
#pragma unroll
        for (int r = 0; r < 4; ++r) {
            int e = m * 16 + quad * 4 + r;
            PRE[(size_t)e * 8192 + row] = acc[m][r] + bias;
        }
}

// ---------------- int16 quantization of W_hh (R5-proven) -----------------
__global__ __launch_bounds__(256) void quant_i16_kernel(
    const float* __restrict__ src, uint4* __restrict__ dst,
    float* __restrict__ scales) {
    const int wave = threadIdx.x >> 6;
    const int lane = threadIdx.x & 63;
    const int row = blockIdx.x * 4 + wave;

    const float4* __restrict__ s4 = (const float4*)(src + (size_t)row * H);
    float4 va[4], vb[4];
    float m = 0.f;
#pragma unroll
    for (int k = 0; k < 4; ++k) {
        const int ci = k * 64 + lane;
        va[k] = s4[2 * ci];
        vb[k] = s4[2 * ci + 1];
        m = fmaxf(m, fmaxf(fmaxf(fabsf(va[k].x), fabsf(va[k].y)),
                           fmaxf(fabsf(va[k].z), fabsf(va[k].w))));
        m = fmaxf(m, fmaxf(fmaxf(fabsf(vb[k].x), fabsf(vb[k].y)),
                           fmaxf(fabsf(vb[k].z), fabsf(vb[k].w))));
    }
#pragma unroll
    for (int off = 32; off > 0; off >>= 1)
        m = fmaxf(m, __shfl_xor(m, off, 64));
    const float inv = (m > 0.f) ? 32767.f / m : 0.f;

    uint4* __restrict__ drow = dst + (size_t)row * 256;
#pragma unroll
    for (int k = 0; k < 4; ++k) {
        const int ci = k * 64 + lane;
        int q0 = (int)rintf(va[k].x * inv), q1 = (int)rintf(va[k].y * inv);
        int q2 = (int)rintf(va[k].z * inv), q3 = (int)rintf(va[k].w * inv);
        int q4 = (int)rintf(vb[k].x * inv), q5 = (int)rintf(vb[k].y * inv);
        int q6 = (int)rintf(vb[k].z * inv), q7 = (int)rintf(vb[k].w * inv);
        uint4 o;
        o.x = ((uint32_t)q0 & 0xffffu) | ((uint32_t)q1 << 16);
        o.y = ((uint32_t)q2 & 0xffffu) | ((uint32_t)q3 << 16);
        o.z = ((uint32_t)q4 & 0xffffu) | ((uint32_t)q5 << 16);
        o.w = ((uint32_t)q6 & 0xffffu) | ((uint32_t)q7 << 16);
        drow[ci] = o;
    }
    if (lane == 0) scales[row] = (m > 0.f) ? m / 32767.f : 0.f;
}

// ---------------- persistent LSTM ----------------------------------------
__device__ __forceinline__ float cvt_lo16(uint32_t u) {
    return (float)((int)(u << 16) >> 16);
}
__device__ __forceinline__ float cvt_hi16(uint32_t u) {
    return (float)((int)u >> 16);
}
__device__ __forceinline__ float i16dot(uint4 w, float4 a, float4 b) {
    return cvt_lo16(w.x) * a.x + cvt_hi16(w.x) * a.y +
           cvt_lo16(w.y) * a.z + cvt_hi16(w.y) * a.w +
           cvt_lo16(w.z) * b.x + cvt_hi16(w.z) * b.y +
           cvt_lo16(w.w) * b.z + cvt_hi16(w.w) * b.w;
}

__device__ __forceinline__ void grid_barrier(int* arr, int bid, int epoch,
                                             int tid) {
    __syncthreads();
    if (tid < 64) {
        if (tid == 0) {
            __threadfence();
            __hip_atomic_store(arr + bid, epoch, __ATOMIC_RELEASE,
                               __HIP_MEMORY_SCOPE_AGENT);
        }
        for (;;) {
            int a0 = __hip_atomic_load(arr + tid, __ATOMIC_RELAXED,
                                       __HIP_MEMORY_SCOPE_AGENT);
            int a1 = __hip_atomic_load(arr + tid + 64, __ATOMIC_RELAXED,
                                       __HIP_MEMORY_SCOPE_AGENT);
            int a2 = __hip_atomic_load(arr + tid + 128, __ATOMIC_RELAXED,
                                       __HIP_MEMORY_SCOPE_AGENT);
            int a3 = __hip_atomic_load(arr + tid + 192, __ATOMIC_RELAXED,
                                       __HIP_MEMORY_SCOPE_AGENT);
            bool ok = a0 >= epoch && a1 >= epoch && a2 >= epoch && a3 >= epoch;
            if (__ballot(ok) == ~0ull) break;
            __builtin_amdgcn_s_sleep(1);
        }
        __threadfence();
    }
    __syncthreads();
}

__global__ __launch_bounds__(NTHR, 1) void lstm_persist(
    const uint4* __restrict__ Whh16,   // [8192][256] uint4 (int16 pairs)
    const float* __restrict__ shh,
    const float* __restrict__ PRE,     // [NEMB][8192]
    const float* __restrict__ dec_act, const float* __restrict__ dec_block,
    float* __restrict__ h0, float* __restrict__ h1,
    float* __restrict__ c_arr,
    float* __restrict__ part0, float* __restrict__ part1,
    int* __restrict__ arr, float* __restrict__ out) {
    __shared__ uint4 Wl[32 * 256];     // 128 KB: row ldr = g*8+jj
    __shared__ float h_s[H];           // 8 KB
    __shared__ float hsl[8];
    __shared__ float logits_s[16];

    const int tid = threadIdx.x;
    const int w = tid >> 6;            // wave = jj (h-element within slice)
    const int lane = tid & 63;
    const int bid = blockIdx.x;

    // stage this block's 32 remapped W_hh rows into LDS (once)
    for (int it = 0; it < 16; ++it) {
        int u = it * NTHR + tid;       // flat uint4 index = ldr*256 + ci
        int ldr = u >> 8, ci = u & 255;
        int grow = (ldr >> 3) * H + bid * 8 + (ldr & 7);
        Wl[u] = Whh16[(size_t)grow * 256 + ci];
    }
    float sc[4];
#pragma unroll
    for (int g = 0; g < 4; ++g) sc[g] = shh[g * H + bid * 8 + w];

    for (int j = tid; j < H; j += NTHR) h_s[j] = 0.f;
    float c_reg = 0.f;
    int emb = ZSLOT;
    int idx = 0;
    __syncthreads();

    for (int t = 0; t < NSTEP; ++t) {
        float* hbuf = (t & 1) ? h1 : h0;
        float* pbuf = (t & 1) ? part1 : part0;

        // prefetch PRE values for this wave's 4 gate rows
        float prev = 0.f;
        if (lane < 4)
            prev = PRE[(size_t)emb * 8192 + lane * H + bid * 8 + w];

        // matvec: 4 gate rows for h-element j = bid*8 + w, from LDS
        float acc[4] = {0.f, 0.f, 0.f, 0.f};
#pragma unroll
        for (int cc = 0; cc < 4; ++cc) {
            const int ci = cc * 64 + lane;
            const float4 ha = ((const float4*)h_s)[2 * ci];
            const float4 hb = ((const float4*)h_s)[2 * ci + 1];
#pragma unroll
            for (int g = 0; g < 4; ++g) {
                uint4 wv4 = Wl[(g * 8 + w) * 256 + ci];
                acc[g] += i16dot(wv4, ha, hb);
            }
        }
#pragma unroll
        for (int off = 32; off > 0; off >>= 1)
#pragma unroll
            for (int g = 0; g < 4; ++g)
                acc[g] += __shfl_xor(acc[g], off, 64);

        float gv[4];
#pragma unroll
        for (int g = 0; g < 4; ++g)
            gv[g] = acc[g] * sc[g] + __shfl(prev, g, 64);

        float cn = sigm(gv[1]) * c_reg + sigm(gv[0]) * tanhf(gv[2]);
        float hn = sigm(gv[3]) * tanhf(cn);
        c_reg = cn;
        if (lane == 0) { hbuf[bid * 8 + w] = hn; hsl[w] = hn; }
        __syncthreads();

        // decode table for this step
        int nclass; const float* dec;
        if (t == 0) { nclass = 4; dec = dec_act; }
        else if (t & 1) {
            int b2 = (t + 1) >> 1; nclass = b2;
            dec = dec_block + (size_t)(b2 - 1) * (NB - 1) * H;
        } else {
            int b2 = t >> 1; nclass = 4;
            dec = dec_act + (size_t)b2 * 4 * H;
        }
        // per-block logit partials over our 8 h-elements
        if (w == 0) {
            for (int cl = 0; cl < nclass; ++cl) {
                float v = (lane < 8)
                              ? dec[(size_t)cl * H + bid * 8 + lane] * hsl[lane]
                              : 0.f;
                v += __shfl_xor(v, 1, 64);
                v += __shfl_xor(v, 2, 64);
                v += __shfl_xor(v, 4, 64);
                if (lane == 0) pbuf[cl * 256 + bid] = v;
            }
        }

        grid_barrier(arr, bid, t + 1, tid);

        // gather h, reduce partials -> logits -> argmax (identical everywhere)
        ((float4*)h_s)[tid] = ((const float4*)hbuf)[tid];
        for (int cl = w; cl < nclass; cl += 8) {
            float4 p4 = ((const float4*)(pbuf + cl * 256))[lane];
            float s = p4.x + p4.y + p4.z + p4.w;
#pragma unroll
            for (int off = 32; off > 0; off >>= 1)
                s += __shfl_xor(s, off, 64);
            if (lane == 0) logits_s[cl] = s;
        }
        __syncthreads();
        {
            float best = logits_s[0]; int bi = 0;
            for (int cl = 1; cl < nclass; ++cl)
                if (logits_s[cl] > best) { best = logits_s[cl]; bi = cl; }
            idx = bi;
        }
        if (t < NSTEP - 1) {
            if ((t & 1) == 0) emb = (t >> 1) * 4 + idx;
            else emb = 44 + ((t - 1) >> 1) * 11 + idx;
        }
        __syncthreads();
    }

    // publish c slices, final barrier, write outputs
    if (lane == 0) c_arr[bid * 8 + w] = c_reg;
    grid_barrier(arr, bid, NSTEP + 1, tid);

    if (bid == 0) { out[tid] = (float)idx; out[tid + NTHR] = (float)idx; }
    float4 hv4 = ((const float4*)h_s)[tid];
    float4 cv4 = ((const float4*)c_arr)[tid];
    float4* oh = (float4*)(out + B);
    float4* oc = (float4*)(out + B + (size_t)B * H);
#pragma unroll
    for (int r = 0; r < 4; ++r) {
        int orow = bid * 4 + r;
        oh[(size_t)orow * (H / 4) + tid] = hv4;
        oc[(size_t)orow * (H / 4) + tid] = cv4;
    }
}

// ---------------- fp32 fallback path (tiny ws) — R1-proven ---------------
__global__ __launch_bounds__(256) void zero_c_kernel(float* __restrict__ cv) {
    int j = blockIdx.x * 256 + threadIdx.x;
    if (j < H) cv[j] = 0.f;
}
__global__ __launch_bounds__(256) void bias_gates_kernel(
    const float* __restrict__ bih, const float* __restrict__ bhh,
    float* __restrict__ gates) {
    int j = blockIdx.x * 256 + threadIdx.x;
    if (j < 4 * H) gates[j] = bih[j] + bhh[j];
}
__global__ __launch_bounds__(256) void gates_kernel(
    const float* __restrict__ Wih, const float* __restrict__ Whh,
    const float* __restrict__ bih, const float* __restrict__ bhh,
    const float* __restrict__ x, const float* __restrict__ h,
    float* __restrict__ gates) {
    const int wave = threadIdx.x >> 6;
    const int lane = threadIdx.x & 63;
    const int row = blockIdx.x * 4 + wave;
    const float4* Wi4 = (const float4*)(Wih + (size_t)row * H);
    const float4* Wh4 = (const float4*)(Whh + (size_t)row * H);
    const float4* x4 = (const float4*)x;
    const float4* h4 = (const float4*)h;
    float acc = 0.f;
#pragma unroll
    for (int k = 0; k < H / 256; ++k) {
        int j = k * 64 + lane;
        float4 wv = Wi4[j]; float4 v = x4[j];
        acc += wv.x * v.x + wv.y * v.y + wv.z * v.z + wv.w * v.w;
    }
#pragma unroll
    for (int k = 0; k < H / 256; ++k) {
        int j = k * 64 + lane;
        float4 wv = Wh4[j]; float4 v = h4[j];
        acc += wv.x * v.x + wv.y * v.y + wv.z * v.z + wv.w * v.w;
    }
    for (int off = 32; off > 0; off >>= 1) acc += __shfl_down(acc, off, 64);
    if (lane == 0) gates[row] = acc + bih[row] + bhh[row];
}
__global__ __launch_bounds__(256) void update_kernel(
    const float* __restrict__ gates,
    float* __restrict__ xv, float* __restrict__ hv, float* __restrict__ cv,
    const float* __restrict__ dec, int nclass,
    const float* __restrict__ enc, int* __restrict__ idx_ptr) {
    const int t = threadIdx.x;
    __shared__ float red[256];
    __shared__ float logits[16];
    __shared__ int sidx;
    float hl[8];
#pragma unroll
    for (int k = 0; k < 8; ++k) {
        int j = k * 256 + t;
        float si = sigm(gates[j]);
        float sf = sigm(gates[H + j]);
        float so = sigm(gates[3 * H + j]);
        float tg = tanhf(gates[2 * H + j]);
        float c2 = sf * cv[j] + si * tg;
        float h2 = so * tanhf(c2);
        cv[j] = c2; hv[j] = h2; hl[k] = h2;
    }
    __syncthreads();
    for (int cl = 0; cl < nclass; ++cl) {
        const float* dr = dec + (size_t)cl * H;
        float p = 0.f;
#pragma unroll
        for (int k = 0; k < 8; ++k) p += hl[k] * dr[k * 256 + t];
        red[t] = p;
        __syncthreads();
        for (int s = 128; s > 0; s >>= 1) {
            if (t < s) red[t] += red[t + s];
            __syncthreads();
        }
        if (t == 0) logits[cl] = red[0];
        __syncthreads();
    }
    if (t == 0) {
        float best = logits[0]; int bi = 0;
        for (int cl = 1; cl < nclass; ++cl)
            if (logits[cl] > best) { best = logits[cl]; bi = cl; }
        sidx = bi; *idx_ptr = bi;
    }
    __syncthreads();
    if (enc != nullptr) {
        const float* er = enc + (size_t)sidx * H;
#pragma unroll
        for (int k = 0; k < 8; ++k) xv[k * 256 + t] = er[k * 256 + t];
    }
}
__global__ __launch_bounds__(256) void final_kernel(
    const float* __restrict__ hv, const float* __restrict__ cv,
    const int* __restrict__ idx_ptr, float* __restrict__ out) {
    const int tid = blockIdx.x * 256 + threadIdx.x;
    const int col = tid & (H / 4 - 1);
    ((float4*)(out + B))[tid] = ((const float4*)hv)[col];
    ((float4*)(out + B + (size_t)B * H))[tid] = ((const float4*)cv)[col];
    if (tid < B) out[tid] = (float)(*idx_ptr);
}

extern "C" void kernel_launch(void* const* d_in, const int* in_sizes, int n_in,
                              void* d_out, int out_size, void* d_ws, size_t ws_size,
                              hipStream_t stream) {
    const float* W_ih      = (const float*)d_in[1];
    const float* W_hh      = (const float*)d_in[2];
    const float* b_ih      = (const float*)d_in[3];
    const float* b_hh      = (const float*)d_in[4];
    const float* enc_act   = (const float*)d_in[5];
    const float* enc_block = (const float*)d_in[6];
    const float* dec_act   = (const float*)d_in[7];
    const float* dec_block = (const float*)d_in[8];
    float* out = (float*)d_out;
    char* ws = (char*)d_ws;

    if (ws_size >= WS_NEED) {
        uint4*    Whh16 = (uint4*)(ws + OFF_WHH);
        float*    shh   = (float*)(ws + OFF_SHH);
        uint32_t* E     = (uint32_t*)(ws + OFF_E);
        float*    PRE   = (float*)(ws + OFF_PRE);
        float*    h0    = (float*)(ws + OFF_H0);
        float*    h1    = (float*)(ws + OFF_H1);
        float*    c_arr = (float*)(ws + OFF_C);
        float*    p0    = (float*)(ws + OFF_P0);
        float*    p1    = (float*)(ws + OFF_P1);
        int*      arr   = (int*)(ws + OFF_ARR);

        build_e_kernel<<<NEMB, 256, 0, stream>>>(enc_act, enc_block, E);
        pre_mfma_kernel<<<256, 128, 0, stream>>>(W_ih, (const uint16_t*)E,
                                                 b_ih, b_hh, PRE);
        quant_i16_kernel<<<2048, 256, 0, stream>>>(W_hh, Whh16, shh);
        hipMemsetAsync(arr, 0, 1024, stream);
        lstm_persist<<<NBLK, NTHR, 0, stream>>>(
            Whh16, shh, PRE, dec_act, dec_block,
            h0, h1, c_arr, p0, p1, arr, out);
        return;
    }

    // fallback: fp32 multi-kernel path
    float* state = (float*)d_ws;
    float* xv = state;
    float* hv = state + H;
    float* cv = state + 2 * H;
    float* gates = state + 3 * H;
    int* idxp = (int*)(state + 7 * H);

    zero_c_kernel<<<8, 256, 0, stream>>>(cv);
    bias_gates_kernel<<<32, 256, 0, stream>>>(b_ih, b_hh, gates);
    update_kernel<<<1, 256, 0, stream>>>(gates, xv, hv, cv, dec_act, 4,
                                         enc_act, idxp);
    for (int bid = 1; bid < NB; ++bid) {
        gates_kernel<<<2048, 256, 0, stream>>>(W_ih, W_hh, b_ih, b_hh,
                                               xv, hv, gates);
        update_kernel<<<1, 256, 0, stream>>>(
            gates, xv, hv, cv,
            dec_block + (size_t)(bid - 1) * (NB - 1) * H, bid,
            enc_block + (size_t)(bid - 1) * (NB - 1) * H, idxp);
        gates_kernel<<<2048, 256, 0, stream>>>(W_ih, W_hh, b_ih, b_hh,
                                               xv, hv, gates);
        update_kernel<<<1, 256, 0, stream>>>(
            gates, xv, hv, cv,
            dec_act + (size_t)bid * 4 * H, 4,
            (bid < NB - 1) ? (enc_act + (size_t)bid * 4 * H) : nullptr, idxp);
    }
    final_kernel<<<2048, 256, 0, stream>>>(hv, cv, idxp, out);
}

// Round 7
// 491.147 us; speedup vs baseline: 2.2907x; 1.5470x over previous
//
#include <hip/hip_runtime.h>
#include <math.h>
#include <stdint.h>

#define H 2048
#define B 1024
#define NB 12
#define NSTEP 23

#define NBLK 256
#define NTHR 512

#define NEMB 176      // 166 used (44 act + 121 block + zero), padded to 176
#define ZSLOT 165

// ---------------- ws layout (bytes) ----------------
#define OFF_WHH  0ull
#define SZ_WHH   (8192ull * 2048ull * 2ull)            // 32 MB int16
#define OFF_SHH  (OFF_WHH + SZ_WHH)
#define SZ_SHH   (8192ull * 4ull)
#define OFF_E    (OFF_SHH + SZ_SHH)
#define SZ_E     ((size_t)NEMB * H * 2ull)             // bf16
#define OFF_PRE  (OFF_E + SZ_E)
#define SZ_PRE   ((size_t)NEMB * 8192ull * 4ull)
#define OFF_H0   (OFF_PRE + SZ_PRE)
#define OFF_H1   (OFF_H0 + 8192ull)
#define OFF_C    (OFF_H1 + 8192ull)
#define OFF_P0   (OFF_C + 8192ull)
#define OFF_P1   (OFF_P0 + 16384ull)
#define OFF_ARR  (OFF_P1 + 16384ull)
#define WS_NEED  (OFF_ARR + 4096ull)

typedef __attribute__((ext_vector_type(8))) short v8s;
typedef __attribute__((ext_vector_type(4))) float v4f;

__device__ __forceinline__ uint32_t bf16rne(float f) {
    uint32_t u = __float_as_uint(f);
    return (u + 0x7fffu + ((u >> 16) & 1u)) >> 16;
}
__device__ __forceinline__ float sigm(float x) { return 1.f / (1.f + expf(-x)); }

// coherent (agent-scope, L2-bypassing) data ops — no cache-wide fences needed
__device__ __forceinline__ void st_agent(float* p, float v) {
    __hip_atomic_store(p, v, __ATOMIC_RELAXED, __HIP_MEMORY_SCOPE_AGENT);
}
__device__ __forceinline__ float ld_agent(const float* p) {
    return __hip_atomic_load(p, __ATOMIC_RELAXED, __HIP_MEMORY_SCOPE_AGENT);
}

// ---------------- gather embeddings -> bf16 E[NEMB][H] -------------------
__global__ __launch_bounds__(256) void build_e_kernel(
    const float* __restrict__ enc_act, const float* __restrict__ enc_block,
    uint32_t* __restrict__ E) {
    const int r = blockIdx.x;
    const int t = threadIdx.x;
    uint4 o = {0, 0, 0, 0};
    const float* src = nullptr;
    if (r < 44) src = enc_act + (size_t)r * H;
    else if (r < 165) src = enc_block + (size_t)(r - 44) * H;
    if (src) {
        float4 a = ((const float4*)src)[2 * t];
        float4 b = ((const float4*)src)[2 * t + 1];
        o.x = bf16rne(a.x) | (bf16rne(a.y) << 16);
        o.y = bf16rne(a.z) | (bf16rne(a.w) << 16);
        o.z = bf16rne(b.x) | (bf16rne(b.y) << 16);
        o.w = bf16rne(b.z) | (bf16rne(b.w) << 16);
    }
    ((uint4*)(E + (size_t)r * (H / 2)))[t] = o;
}

// ---------------- PRE = E @ W_ih^T + (b_ih+b_hh), bf16 MFMA --------------
__global__ __launch_bounds__(128) void pre_mfma_kernel(
    const float* __restrict__ W,
    const uint16_t* __restrict__ E,
    const float* __restrict__ bih, const float* __restrict__ bhh,
    float* __restrict__ PRE) {
    const int wv = threadIdx.x >> 6;
    const int lane = threadIdx.x & 63;
    const int tN = blockIdx.x * 2 + wv;
    const int l16 = lane & 15;
    const int quad = lane >> 4;
    const int row = tN * 16 + l16;
    const float* wp = W + (size_t)row * H;

    v4f acc[11];
#pragma unroll
    for (int m = 0; m < 11; ++m) acc[m] = (v4f){0.f, 0.f, 0.f, 0.f};

    for (int ks = 0; ks < 64; ++ks) {
        const int ko = ks * 32 + quad * 8;
        float4 wa = *(const float4*)(wp + ko);
        float4 wb = *(const float4*)(wp + ko + 4);
        v8s bfrag;
        bfrag[0] = (short)bf16rne(wa.x); bfrag[1] = (short)bf16rne(wa.y);
        bfrag[2] = (short)bf16rne(wa.z); bfrag[3] = (short)bf16rne(wa.w);
        bfrag[4] = (short)bf16rne(wb.x); bfrag[5] = (short)bf16rne(wb.y);
        bfrag[6] = (short)bf16rne(wb.z); bfrag[7] = (short)bf16rne(wb.w);
#pragma unroll
        for (int m = 0; m < 11; ++m) {
            v8s afrag = *(const v8s*)(E + (size_t)(m * 16 + l16) * H + ko);
            acc[m] = __builtin_amdgcn_mfma_f32_16x16x32_bf16(afrag, bfrag,
                                                             acc[m], 0, 0, 0);
        }
    }
    const float bias = bih[row] + bhh[row];
#pragma unroll
    for (int m = 0; m < 11; ++m)
#pragma unroll
        for (int r = 0; r < 4; ++r) {
            int e = m * 16 + quad * 4 + r;
            PRE[(size_t)e * 8192 + row] = acc[m][r] + bias;
        }
}

// ---------------- int16 quantization of W_hh -----------------------------
__global__ __launch_bounds__(256) void quant_i16_kernel(
    const float* __restrict__ src, uint4* __restrict__ dst,
    float* __restrict__ scales) {
    const int wave = threadIdx.x >> 6;
    const int lane = threadIdx.x & 63;
    const int row = blockIdx.x * 4 + wave;

    const float4* __restrict__ s4 = (const float4*)(src + (size_t)row * H);
    float4 va[4], vb[4];
    float m = 0.f;
#pragma unroll
    for (int k = 0; k < 4; ++k) {
        const int ci = k * 64 + lane;
        va[k] = s4[2 * ci];
        vb[k] = s4[2 * ci + 1];
        m = fmaxf(m, fmaxf(fmaxf(fabsf(va[k].x), fabsf(va[k].y)),
                           fmaxf(fabsf(va[k].z), fabsf(va[k].w))));
        m = fmaxf(m, fmaxf(fmaxf(fabsf(vb[k].x), fabsf(vb[k].y)),
                           fmaxf(fabsf(vb[k].z), fabsf(vb[k].w))));
    }
#pragma unroll
    for (int off = 32; off > 0; off >>= 1)
        m = fmaxf(m, __shfl_xor(m, off, 64));
    const float inv = (m > 0.f) ? 32767.f / m : 0.f;

    uint4* __restrict__ drow = dst + (size_t)row * 256;
#pragma unroll
    for (int k = 0; k < 4; ++k) {
        const int ci = k * 64 + lane;
        int q0 = (int)rintf(va[k].x * inv), q1 = (int)rintf(va[k].y * inv);
        int q2 = (int)rintf(va[k].z * inv), q3 = (int)rintf(va[k].w * inv);
        int q4 = (int)rintf(vb[k].x * inv), q5 = (int)rintf(vb[k].y * inv);
        int q6 = (int)rintf(vb[k].z * inv), q7 = (int)rintf(vb[k].w * inv);
        uint4 o;
        o.x = ((uint32_t)q0 & 0xffffu) | ((uint32_t)q1 << 16);
        o.y = ((uint32_t)q2 & 0xffffu) | ((uint32_t)q3 << 16);
        o.z = ((uint32_t)q4 & 0xffffu) | ((uint32_t)q5 << 16);
        o.w = ((uint32_t)q6 & 0xffffu) | ((uint32_t)q7 << 16);
        drow[ci] = o;
    }
    if (lane == 0) scales[row] = (m > 0.f) ? m / 32767.f : 0.f;
}

// ---------------- persistent LSTM ----------------------------------------
__device__ __forceinline__ float cvt_lo16(uint32_t u) {
    return (float)((int)(u << 16) >> 16);
}
__device__ __forceinline__ float cvt_hi16(uint32_t u) {
    return (float)((int)u >> 16);
}
__device__ __forceinline__ float i16dot(uint4 w, float4 a, float4 b) {
    return cvt_lo16(w.x) * a.x + cvt_hi16(w.x) * a.y +
           cvt_lo16(w.y) * a.z + cvt_hi16(w.y) * a.w +
           cvt_lo16(w.z) * b.x + cvt_hi16(w.z) * b.y +
           cvt_lo16(w.w) * b.z + cvt_hi16(w.w) * b.w;
}

// fence-free grid barrier: all cross-block data uses agent-scope (coherent)
// ops, so __syncthreads' vmcnt drain is sufficient release; no wbl2/inv.
__device__ __forceinline__ void grid_barrier_nf(int* arr, int bid, int epoch,
                                                int tid) {
    __syncthreads();   // drains all waves' outstanding (coherent) stores
    if (tid < 64) {
        if (tid == 0) {
            __builtin_amdgcn_s_waitcnt(0);
            __hip_atomic_store(arr + bid, epoch, __ATOMIC_RELAXED,
                               __HIP_MEMORY_SCOPE_AGENT);
        }
        int a0 = 0, a1 = 0, a2 = 0, a3 = 0;
        long guard = 0;
        for (;;) {
            if (a0 < epoch)
                a0 = __hip_atomic_load(arr + tid, __ATOMIC_RELAXED,
                                       __HIP_MEMORY_SCOPE_AGENT);
            if (a1 < epoch)
                a1 = __hip_atomic_load(arr + tid + 64, __ATOMIC_RELAXED,
                                       __HIP_MEMORY_SCOPE_AGENT);
            if (a2 < epoch)
                a2 = __hip_atomic_load(arr + tid + 128, __ATOMIC_RELAXED,
                                       __HIP_MEMORY_SCOPE_AGENT);
            if (a3 < epoch)
                a3 = __hip_atomic_load(arr + tid + 192, __ATOMIC_RELAXED,
                                       __HIP_MEMORY_SCOPE_AGENT);
            bool ok = a0 >= epoch && a1 >= epoch && a2 >= epoch && a3 >= epoch;
            if (__ballot(ok) == ~0ull) break;
            if (++guard > (1L << 27)) break;  // failsafe: never hard-hang
            __builtin_amdgcn_s_sleep(1);
        }
        asm volatile("" ::: "memory");
    }
    __syncthreads();
}

__global__ __launch_bounds__(NTHR, 1) void lstm_persist(
    const uint4* __restrict__ Whh16,
    const float* __restrict__ shh,
    const float* __restrict__ PRE,
    const float* __restrict__ dec_act, const float* __restrict__ dec_block,
    float* __restrict__ h0, float* __restrict__ h1,
    float* __restrict__ c_arr,
    float* __restrict__ part0, float* __restrict__ part1,
    int* __restrict__ arr, float* __restrict__ out) {
    __shared__ uint4 Wl[32 * 256];     // 128 KB
    __shared__ float h_s[H];           // 8 KB
    __shared__ float hsl[8];
    __shared__ float logits_s[16];

    const int tid = threadIdx.x;
    const int w = tid >> 6;
    const int lane = tid & 63;
    const int bid = blockIdx.x;

    for (int it = 0; it < 16; ++it) {
        int u = it * NTHR + tid;
        int ldr = u >> 8, ci = u & 255;
        int grow = (ldr >> 3) * H + bid * 8 + (ldr & 7);
        Wl[u] = Whh16[(size_t)grow * 256 + ci];
    }
    float sc[4];
#pragma unroll
    for (int g = 0; g < 4; ++g) sc[g] = shh[g * H + bid * 8 + w];

    for (int j = tid; j < H; j += NTHR) h_s[j] = 0.f;
    float c_reg = 0.f;
    int emb = ZSLOT;
    int idx = 0;
    __syncthreads();

    for (int t = 0; t < NSTEP; ++t) {
        float* hbuf = (t & 1) ? h1 : h0;
        float* pbuf = (t & 1) ? part1 : part0;

        float prev = 0.f;
        if (lane < 4)
            prev = PRE[(size_t)emb * 8192 + lane * H + bid * 8 + w];

        float acc[4] = {0.f, 0.f, 0.f, 0.f};
#pragma unroll
        for (int cc = 0; cc < 4; ++cc) {
            const int ci = cc * 64 + lane;
            const float4 ha = ((const float4*)h_s)[2 * ci];
            const float4 hb = ((const float4*)h_s)[2 * ci + 1];
#pragma unroll
            for (int g = 0; g < 4; ++g) {
                uint4 wv4 = Wl[(g * 8 + w) * 256 + ci];
                acc[g] += i16dot(wv4, ha, hb);
            }
        }
#pragma unroll
        for (int off = 32; off > 0; off >>= 1)
#pragma unroll
            for (int g = 0; g < 4; ++g)
                acc[g] += __shfl_xor(acc[g], off, 64);

        float gv[4];
#pragma unroll
        for (int g = 0; g < 4; ++g)
            gv[g] = acc[g] * sc[g] + __shfl(prev, g, 64);

        float cn = sigm(gv[1]) * c_reg + sigm(gv[0]) * tanhf(gv[2]);
        float hn = sigm(gv[3]) * tanhf(cn);
        c_reg = cn;
        if (lane == 0) { st_agent(hbuf + bid * 8 + w, hn); hsl[w] = hn; }
        __syncthreads();

        int nclass; const float* dec;
        if (t == 0) { nclass = 4; dec = dec_act; }
        else if (t & 1) {
            int b2 = (t + 1) >> 1; nclass = b2;
            dec = dec_block + (size_t)(b2 - 1) * (NB - 1) * H;
        } else {
            int b2 = t >> 1; nclass = 4;
            dec = dec_act + (size_t)b2 * 4 * H;
        }
        if (w == 0) {
            for (int cl = 0; cl < nclass; ++cl) {
                float v = (lane < 8)
                              ? dec[(size_t)cl * H + bid * 8 + lane] * hsl[lane]
                              : 0.f;
                v += __shfl_xor(v, 1, 64);
                v += __shfl_xor(v, 2, 64);
                v += __shfl_xor(v, 4, 64);
                if (lane == 0) st_agent(pbuf + cl * 256 + bid, v);
            }
        }

        grid_barrier_nf(arr, bid, t + 1, tid);

        // gather h (coherent loads), reduce partials -> logits -> argmax
        {
            const float* hp = hbuf + tid * 4;
            float4 hv;
            hv.x = ld_agent(hp);     hv.y = ld_agent(hp + 1);
            hv.z = ld_agent(hp + 2); hv.w = ld_agent(hp + 3);
            ((float4*)h_s)[tid] = hv;
        }
        for (int cl = w; cl < nclass; cl += 8) {
            const float* pp = pbuf + cl * 256 + lane * 4;
            float s = ld_agent(pp) + ld_agent(pp + 1) +
                      ld_agent(pp + 2) + ld_agent(pp + 3);
#pragma unroll
            for (int off = 32; off > 0; off >>= 1)
                s += __shfl_xor(s, off, 64);
            if (lane == 0) logits_s[cl] = s;
        }
        __syncthreads();
        {
            float best = logits_s[0]; int bi = 0;
            for (int cl = 1; cl < nclass; ++cl)
                if (logits_s[cl] > best) { best = logits_s[cl]; bi = cl; }
            idx = bi;
        }
        if (t < NSTEP - 1) {
            if ((t & 1) == 0) emb = (t >> 1) * 4 + idx;
            else emb = 44 + ((t - 1) >> 1) * 11 + idx;
        }
        __syncthreads();
    }

    if (lane == 0) st_agent(c_arr + bid * 8 + w, c_reg);
    grid_barrier_nf(arr, bid, NSTEP + 1, tid);

    if (bid == 0) { out[tid] = (float)idx; out[tid + NTHR] = (float)idx; }
    float4 hv4 = ((const float4*)h_s)[tid];
    float4 cv4;
    {
        const float* cp = c_arr + tid * 4;
        cv4.x = ld_agent(cp);     cv4.y = ld_agent(cp + 1);
        cv4.z = ld_agent(cp + 2); cv4.w = ld_agent(cp + 3);
    }
    float4* oh = (float4*)(out + B);
    float4* oc = (float4*)(out + B + (size_t)B * H);
#pragma unroll
    for (int r = 0; r < 4; ++r) {
        int orow = bid * 4 + r;
        oh[(size_t)orow * (H / 4) + tid] = hv4;
        oc[(size_t)orow * (H / 4) + tid] = cv4;
    }
}

// ---------------- fp32 fallback path (tiny ws) — R1-proven ---------------
__global__ __launch_bounds__(256) void zero_c_kernel(float* __restrict__ cv) {
    int j = blockIdx.x * 256 + threadIdx.x;
    if (j < H) cv[j] = 0.f;
}
__global__ __launch_bounds__(256) void bias_gates_kernel(
    const float* __restrict__ bih, const float* __restrict__ bhh,
    float* __restrict__ gates) {
    int j = blockIdx.x * 256 + threadIdx.x;
    if (j < 4 * H) gates[j] = bih[j] + bhh[j];
}
__global__ __launch_bounds__(256) void gates_kernel(
    const float* __restrict__ Wih, const float* __restrict__ Whh,
    const float* __restrict__ bih, const float* __restrict__ bhh,
    const float* __restrict__ x, const float* __restrict__ h,
    float* __restrict__ gates) {
    const int wave = threadIdx.x >> 6;
    const int lane = threadIdx.x & 63;
    const int row = blockIdx.x * 4 + wave;
    const float4* Wi4 = (const float4*)(Wih + (size_t)row * H);
    const float4* Wh4 = (const float4*)(Whh + (size_t)row * H);
    const float4* x4 = (const float4*)x;
    const float4* h4 = (const float4*)h;
    float acc = 0.f;
#pragma unroll
    for (int k = 0; k < H / 256; ++k) {
        int j = k * 64 + lane;
        float4 wv = Wi4[j]; float4 v = x4[j];
        acc += wv.x * v.x + wv.y * v.y + wv.z * v.z + wv.w * v.w;
    }
#pragma unroll
    for (int k = 0; k < H / 256; ++k) {
        int j = k * 64 + lane;
        float4 wv = Wh4[j]; float4 v = h4[j];
        acc += wv.x * v.x + wv.y * v.y + wv.z * v.z + wv.w * v.w;
    }
    for (int off = 32; off > 0; off >>= 1) acc += __shfl_down(acc, off, 64);
    if (lane == 0) gates[row] = acc + bih[row] + bhh[row];
}
__global__ __launch_bounds__(256) void update_kernel(
    const float* __restrict__ gates,
    float* __restrict__ xv, float* __restrict__ hv, float* __restrict__ cv,
    const float* __restrict__ dec, int nclass,
    const float* __restrict__ enc, int* __restrict__ idx_ptr) {
    const int t = threadIdx.x;
    __shared__ float red[256];
    __shared__ float logits[16];
    __shared__ int sidx;
    float hl[8];
#pragma unroll
    for (int k = 0; k < 8; ++k) {
        int j = k * 256 + t;
        float si = sigm(gates[j]);
        float sf = sigm(gates[H + j]);
        float so = sigm(gates[3 * H + j]);
        float tg = tanhf(gates[2 * H + j]);
        float c2 = sf * cv[j] + si * tg;
        float h2 = so * tanhf(c2);
        cv[j] = c2; hv[j] = h2; hl[k] = h2;
    }
    __syncthreads();
    for (int cl = 0; cl < nclass; ++cl) {
        const float* dr = dec + (size_t)cl * H;
        float p = 0.f;
#pragma unroll
        for (int k = 0; k < 8; ++k) p += hl[k] * dr[k * 256 + t];
        red[t] = p;
        __syncthreads();
        for (int s = 128; s > 0; s >>= 1) {
            if (t < s) red[t] += red[t + s];
            __syncthreads();
        }
        if (t == 0) logits[cl] = red[0];
        __syncthreads();
    }
    if (t == 0) {
        float best = logits[0]; int bi = 0;
        for (int cl = 1; cl < nclass; ++cl)
            if (logits[cl] > best) { best = logits[cl]; bi = cl; }
        sidx = bi; *idx_ptr = bi;
    }
    __syncthreads();
    if (enc != nullptr) {
        const float* er = enc + (size_t)sidx * H;
#pragma unroll
        for (int k = 0; k < 8; ++k) xv[k * 256 + t] = er[k * 256 + t];
    }
}
__global__ __launch_bounds__(256) void final_kernel(
    const float* __restrict__ hv, const float* __restrict__ cv,
    const int* __restrict__ idx_ptr, float* __restrict__ out) {
    const int tid = blockIdx.x * 256 + threadIdx.x;
    const int col = tid & (H / 4 - 1);
    ((float4*)(out + B))[tid] = ((const float4*)hv)[col];
    ((float4*)(out + B + (size_t)B * H))[tid] = ((const float4*)cv)[col];
    if (tid < B) out[tid] = (float)(*idx_ptr);
}

extern "C" void kernel_launch(void* const* d_in, const int* in_sizes, int n_in,
                              void* d_out, int out_size, void* d_ws, size_t ws_size,
                              hipStream_t stream) {
    const float* W_ih      = (const float*)d_in[1];
    const float* W_hh      = (const float*)d_in[2];
    const float* b_ih      = (const float*)d_in[3];
    const float* b_hh      = (const float*)d_in[4];
    const float* enc_act   = (const float*)d_in[5];
    const float* enc_block = (const float*)d_in[6];
    const float* dec_act   = (const float*)d_in[7];
    const float* dec_block = (const float*)d_in[8];
    float* out = (float*)d_out;
    char* ws = (char*)d_ws;

    if (ws_size >= WS_NEED) {
        uint4*    Whh16 = (uint4*)(ws + OFF_WHH);
        float*    shh   = (float*)(ws + OFF_SHH);
        uint32_t* E     = (uint32_t*)(ws + OFF_E);
        float*    PRE   = (float*)(ws + OFF_PRE);
        float*    h0    = (float*)(ws + OFF_H0);
        float*    h1    = (float*)(ws + OFF_H1);
        float*    c_arr = (float*)(ws + OFF_C);
        float*    p0    = (float*)(ws + OFF_P0);
        float*    p1    = (float*)(ws + OFF_P1);
        int*      arr   = (int*)(ws + OFF_ARR);

        build_e_kernel<<<NEMB, 256, 0, stream>>>(enc_act, enc_block, E);
        pre_mfma_kernel<<<256, 128, 0, stream>>>(W_ih, (const uint16_t*)E,
                                                 b_ih, b_hh, PRE);
        quant_i16_kernel<<<2048, 256, 0, stream>>>(W_hh, Whh16, shh);
        hipMemsetAsync(arr, 0, 1024, stream);
        lstm_persist<<<NBLK, NTHR, 0, stream>>>(
            Whh16, shh, PRE, dec_act, dec_block,
            h0, h1, c_arr, p0, p1, arr, out);
        return;
    }

    // fallback: fp32 multi-kernel path
    float* state = (float*)d_ws;
    float* xv = state;
    float* hv = state + H;
    float* cv = state + 2 * H;
    float* gates = state + 3 * H;
    int* idxp = (int*)(state + 7 * H);

    zero_c_kernel<<<8, 256, 0, stream>>>(cv);
    bias_gates_kernel<<<32, 256, 0, stream>>>(b_ih, b_hh, gates);
    update_kernel<<<1, 256, 0, stream>>>(gates, xv, hv, cv, dec_act, 4,
                                         enc_act, idxp);
    for (int bid = 1; bid < NB; ++bid) {
        gates_kernel<<<2048, 256, 0, stream>>>(W_ih, W_hh, b_ih, b_hh,
                                               xv, hv, gates);
        update_kernel<<<1, 256, 0, stream>>>(
            gates, xv, hv, cv,
            dec_block + (size_t)(bid - 1) * (NB - 1) * H, bid,
            enc_block + (size_t)(bid - 1) * (NB - 1) * H, idxp);
        gates_kernel<<<2048, 256, 0, stream>>>(W_ih, W_hh, b_ih, b_hh,
                                               xv, hv, gates);
        update_kernel<<<1, 256, 0, stream>>>(
            gates, xv, hv, cv,
            dec_act + (size_t)bid * 4 * H, 4,
            (bid < NB - 1) ? (enc_act + (size_t)bid * 4 * H) : nullptr, idxp);
    }
    final_kernel<<<2048, 256, 0, stream>>>(hv, cv, idxp, out);
}

// Round 9
// 468.631 us; speedup vs baseline: 2.4008x; 1.0480x over previous
//
#include <hip/hip_runtime.h>
#include <math.h>
#include <stdint.h>

#define H 2048
#define B 1024
#define NB 12
#define NSTEP 23

#define NBLK 256
#define NTHR 512

#define NEMB 176      // 166 used (44 act + 121 block + zero), padded
#define ZSLOT 165
#define PRE_N 1441792ull          // NEMB * 8192 floats

// ---------------- ws layout (bytes) ----------------
#define OFF_WHH  0ull
#define SZ_WHH   (8192ull * 2048ull * 2ull)            // 32 MB int16
#define OFF_SHH  (OFF_WHH + SZ_WHH)
#define SZ_SHH   (8192ull * 4ull)
#define OFF_E    (OFF_SHH + SZ_SHH)
#define SZ_E     ((size_t)NEMB * H * 2ull)             // bf16
#define OFF_PRE  (OFF_E + SZ_E)
#define SZ_PRE   (PRE_N * 4ull)                        // 5.77 MB
#define OFF_PREP (OFF_PRE + SZ_PRE)
#define SZ_PREP  (4ull * PRE_N * 4ull)                 // 23 MB
#define OFF_H0   (OFF_PREP + SZ_PREP)
#define OFF_H1   (OFF_H0 + 8192ull)
#define OFF_C    (OFF_H1 + 8192ull)
#define OFF_P0   (OFF_C + 8192ull)
#define OFF_P1   (OFF_P0 + 16384ull)
#define OFF_ARR  (OFF_P1 + 16384ull)
#define WS_NEED  (OFF_ARR + 4096ull)

typedef __attribute__((ext_vector_type(8))) short v8s;
typedef __attribute__((ext_vector_type(4))) float v4f;

__device__ __forceinline__ uint32_t bf16rne(float f) {
    uint32_t u = __float_as_uint(f);
    return (u + 0x7fffu + ((u >> 16) & 1u)) >> 16;
}
__device__ __forceinline__ float sigm(float x) { return 1.f / (1.f + expf(-x)); }

// coherent (bypass L1+L2, hit coherence point) scalar atomic store
__device__ __forceinline__ void st_agent(float* p, float v) {
    __hip_atomic_store(p, v, __ATOMIC_RELAXED, __HIP_MEMORY_SCOPE_AGENT);
}
__device__ __forceinline__ void st_agent_i(int* p, int v) {
    __hip_atomic_store(p, v, __ATOMIC_RELAXED, __HIP_MEMORY_SCOPE_AGENT);
}
// wide coherent loads: load + wait fused in one asm block ("=v" output only)
__device__ __forceinline__ float4 ld_agent_f4(const float* p) {
    float4 r;
    asm volatile("global_load_dwordx4 %0, %1, off sc0 sc1\n\t"
                 "s_waitcnt vmcnt(0)"
                 : "=v"(r) : "v"(p) : "memory");
    return r;
}
__device__ __forceinline__ int4 ld_agent_i4(const int* p) {
    int4 r;
    asm volatile("global_load_dwordx4 %0, %1, off sc0 sc1\n\t"
                 "s_waitcnt vmcnt(0)"
                 : "=v"(r) : "v"(p) : "memory");
    return r;
}

// ---------------- gather embeddings -> bf16 E[NEMB][H] -------------------
__global__ __launch_bounds__(256) void build_e_kernel(
    const float* __restrict__ enc_act, const float* __restrict__ enc_block,
    uint32_t* __restrict__ E) {
    const int r = blockIdx.x;
    const int t = threadIdx.x;
    uint4 o = {0, 0, 0, 0};
    const float* src = nullptr;
    if (r < 44) src = enc_act + (size_t)r * H;
    else if (r < 165) src = enc_block + (size_t)(r - 44) * H;
    if (src) {
        float4 a = ((const float4*)src)[2 * t];
        float4 b = ((const float4*)src)[2 * t + 1];
        o.x = bf16rne(a.x) | (bf16rne(a.y) << 16);
        o.y = bf16rne(a.z) | (bf16rne(a.w) << 16);
        o.z = bf16rne(b.x) | (bf16rne(b.y) << 16);
        o.w = bf16rne(b.z) | (bf16rne(b.w) << 16);
    }
    ((uint4*)(E + (size_t)r * (H / 2)))[t] = o;
}

// ---------------- PREP[ksl] = E @ W_ih^T (K-slice), bf16 MFMA ------------
// grid: 1024 blocks x 128 thr; blk=blockIdx&255 -> tN, ksl=blockIdx>>8
__global__ __launch_bounds__(128) void pre_mfma_kernel(
    const float* __restrict__ W,
    const uint16_t* __restrict__ E,
    float* __restrict__ PREP) {
    const int wv = threadIdx.x >> 6;
    const int lane = threadIdx.x & 63;
    const int blk = blockIdx.x & 255;
    const int ksl = blockIdx.x >> 8;             // 0..3
    const int tN = blk * 2 + wv;
    const int l16 = lane & 15;
    const int quad = lane >> 4;
    const int row = tN * 16 + l16;
    const float* wp = W + (size_t)row * H;

    v4f acc[11];
#pragma unroll
    for (int m = 0; m < 11; ++m) acc[m] = (v4f){0.f, 0.f, 0.f, 0.f};

    for (int ks = ksl * 16; ks < ksl * 16 + 16; ++ks) {
        const int ko = ks * 32 + quad * 8;
        float4 wa = *(const float4*)(wp + ko);
        float4 wb = *(const float4*)(wp + ko + 4);
        v8s bfrag;
        bfrag[0] = (short)bf16rne(wa.x); bfrag[1] = (short)bf16rne(wa.y);
        bfrag[2] = (short)bf16rne(wa.z); bfrag[3] = (short)bf16rne(wa.w);
        bfrag[4] = (short)bf16rne(wb.x); bfrag[5] = (short)bf16rne(wb.y);
        bfrag[6] = (short)bf16rne(wb.z); bfrag[7] = (short)bf16rne(wb.w);
#pragma unroll
        for (int m = 0; m < 11; ++m) {
            v8s afrag = *(const v8s*)(E + (size_t)(m * 16 + l16) * H + ko);
            acc[m] = __builtin_amdgcn_mfma_f32_16x16x32_bf16(afrag, bfrag,
                                                             acc[m], 0, 0, 0);
        }
    }
    float* dst = PREP + (size_t)ksl * PRE_N;
#pragma unroll
    for (int m = 0; m < 11; ++m)
#pragma unroll
        for (int r = 0; r < 4; ++r) {
            int e = m * 16 + quad * 4 + r;
            dst[(size_t)e * 8192 + row] = acc[m][r];
        }
}

// PRE = sum_ksl PREP[ksl] + (b_ih+b_hh) broadcast per row
// grid: 1408 x 256, one float4 per thread (360448 float4s)
__global__ __launch_bounds__(256) void pre_reduce_kernel(
    const float* __restrict__ PREP,
    const float* __restrict__ bih, const float* __restrict__ bhh,
    float* __restrict__ PRE) {
    const int i = blockIdx.x * 256 + threadIdx.x;
    float4 a = ((const float4*)PREP)[i];
    float4 b = ((const float4*)(PREP + PRE_N))[i];
    float4 c = ((const float4*)(PREP + 2 * PRE_N))[i];
    float4 d = ((const float4*)(PREP + 3 * PRE_N))[i];
    const int r4 = i & 2047;
    float4 bi = ((const float4*)bih)[r4];
    float4 bh = ((const float4*)bhh)[r4];
    float4 o;
    o.x = a.x + b.x + c.x + d.x + bi.x + bh.x;
    o.y = a.y + b.y + c.y + d.y + bi.y + bh.y;
    o.z = a.z + b.z + c.z + d.z + bi.z + bh.z;
    o.w = a.w + b.w + c.w + d.w + bi.w + bh.w;
    ((float4*)PRE)[i] = o;
}

// ---------------- int16 quantization of W_hh -----------------------------
__global__ __launch_bounds__(256) void quant_i16_kernel(
    const float* __restrict__ src, uint4* __restrict__ dst,
    float* __restrict__ scales) {
    const int wave = threadIdx.x >> 6;
    const int lane = threadIdx.x & 63;
    const int row = blockIdx.x * 4 + wave;

    const float4* __restrict__ s4 = (const float4*)(src + (size_t)row * H);
    float4 va[4], vb[4];
    float m = 0.f;
#pragma unroll
    for (int k = 0; k < 4; ++k) {
        const int ci = k * 64 + lane;
        va[k] = s4[2 * ci];
        vb[k] = s4[2 * ci + 1];
        m = fmaxf(m, fmaxf(fmaxf(fabsf(va[k].x), fabsf(va[k].y)),
                           fmaxf(fabsf(va[k].z), fabsf(va[k].w))));
        m = fmaxf(m, fmaxf(fmaxf(fabsf(vb[k].x), fabsf(vb[k].y)),
                           fmaxf(fabsf(vb[k].z), fabsf(vb[k].w))));
    }
#pragma unroll
    for (int off = 32; off > 0; off >>= 1)
        m = fmaxf(m, __shfl_xor(m, off, 64));
    const float inv = (m > 0.f) ? 32767.f / m : 0.f;

    uint4* __restrict__ drow = dst + (size_t)row * 256;
#pragma unroll
    for (int k = 0; k < 4; ++k) {
        const int ci = k * 64 + lane;
        int q0 = (int)rintf(va[k].x * inv), q1 = (int)rintf(va[k].y * inv);
        int q2 = (int)rintf(va[k].z * inv), q3 = (int)rintf(va[k].w * inv);
        int q4 = (int)rintf(vb[k].x * inv), q5 = (int)rintf(vb[k].y * inv);
        int q6 = (int)rintf(vb[k].z * inv), q7 = (int)rintf(vb[k].w * inv);
        uint4 o;
        o.x = ((uint32_t)q0 & 0xffffu) | ((uint32_t)q1 << 16);
        o.y = ((uint32_t)q2 & 0xffffu) | ((uint32_t)q3 << 16);
        o.z = ((uint32_t)q4 & 0xffffu) | ((uint32_t)q5 << 16);
        o.w = ((uint32_t)q6 & 0xffffu) | ((uint32_t)q7 << 16);
        drow[ci] = o;
    }
    if (lane == 0) scales[row] = (m > 0.f) ? m / 32767.f : 0.f;
}

// ---------------- persistent LSTM ----------------------------------------
__device__ __forceinline__ float cvt_lo16(uint32_t u) {
    return (float)((int)(u << 16) >> 16);
}
__device__ __forceinline__ float cvt_hi16(uint32_t u) {
    return (float)((int)u >> 16);
}
__device__ __forceinline__ float i16dot(uint4 w, float4 a, float4 b) {
    return cvt_lo16(w.x) * a.x + cvt_hi16(w.x) * a.y +
           cvt_lo16(w.y) * a.z + cvt_hi16(w.y) * a.w +
           cvt_lo16(w.z) * b.x + cvt_hi16(w.z) * b.y +
           cvt_lo16(w.w) * b.z + cvt_hi16(w.w) * b.w;
}

// fence-free grid barrier; packed flag poll: lane checks 4 flags / dwordx4
__device__ __forceinline__ void grid_barrier_nf(int* arr, int bid, int epoch,
                                                int tid) {
    __syncthreads();   // drains all waves' outstanding (coherent) stores
    if (tid < 64) {
        if (tid == 0) {
            __builtin_amdgcn_s_waitcnt(0);
            st_agent_i(arr + bid, epoch);
        }
        long guard = 0;
        for (;;) {
            int4 f = ld_agent_i4(arr + tid * 4);
            bool ok = f.x >= epoch && f.y >= epoch &&
                      f.z >= epoch && f.w >= epoch;
            if (__ballot(ok) == ~0ull) break;
            if (++guard > (1L << 26)) break;  // failsafe: never hard-hang
            __builtin_amdgcn_s_sleep(1);
        }
        asm volatile("" ::: "memory");
    }
    __syncthreads();
}

__global__ __launch_bounds__(NTHR, 1) void lstm_persist(
    const uint4* __restrict__ Whh16,
    const float* __restrict__ shh,
    const float* __restrict__ PRE,
    const float* __restrict__ dec_act, const float* __restrict__ dec_block,
    float* __restrict__ h0, float* __restrict__ h1,
    float* __restrict__ c_arr,
    float* __restrict__ part0, float* __restrict__ part1,
    int* __restrict__ arr, float* __restrict__ out) {
    __shared__ uint4 Wl[32 * 256];     // 128 KB
    __shared__ float h_s[H];           // 8 KB
    __shared__ float hsl[8];
    __shared__ float logits_s[16];

    const int tid = threadIdx.x;
    const int w = tid >> 6;
    const int lane = tid & 63;
    const int bid = blockIdx.x;

    for (int it = 0; it < 16; ++it) {
        int u = it * NTHR + tid;
        int ldr = u >> 8, ci = u & 255;
        int grow = (ldr >> 3) * H + bid * 8 + (ldr & 7);
        Wl[u] = Whh16[(size_t)grow * 256 + ci];
    }
    float sc[4];
#pragma unroll
    for (int g = 0; g < 4; ++g) sc[g] = shh[g * H + bid * 8 + w];

    for (int j = tid; j < H; j += NTHR) h_s[j] = 0.f;
    float c_reg = 0.f;
    int emb = ZSLOT;
    int idx = 0;
    __syncthreads();

    for (int t = 0; t < NSTEP; ++t) {
        float* hbuf = (t & 1) ? h1 : h0;
        float* pbuf = (t & 1) ? part1 : part0;

        float prev = 0.f;
        if (lane < 4)
            prev = PRE[(size_t)emb * 8192 + lane * H + bid * 8 + w];

        float acc[4] = {0.f, 0.f, 0.f, 0.f};
#pragma unroll
        for (int cc = 0; cc < 4; ++cc) {
            const int ci = cc * 64 + lane;
            const float4 ha = ((const float4*)h_s)[2 * ci];
            const float4 hb = ((const float4*)h_s)[2 * ci + 1];
#pragma unroll
            for (int g = 0; g < 4; ++g) {
                uint4 wv4 = Wl[(g * 8 + w) * 256 + ci];
                acc[g] += i16dot(wv4, ha, hb);
            }
        }
#pragma unroll
        for (int off = 32; off > 0; off >>= 1)
#pragma unroll
            for (int g = 0; g < 4; ++g)
                acc[g] += __shfl_xor(acc[g], off, 64);

        float gv[4];
#pragma unroll
        for (int g = 0; g < 4; ++g)
            gv[g] = acc[g] * sc[g] + __shfl(prev, g, 64);

        float cn = sigm(gv[1]) * c_reg + sigm(gv[0]) * tanhf(gv[2]);
        float hn = sigm(gv[3]) * tanhf(cn);
        c_reg = cn;
        if (lane == 0) { st_agent(hbuf + bid * 8 + w, hn); hsl[w] = hn; }
        __syncthreads();

        int nclass; const float* dec;
        if (t == 0) { nclass = 4; dec = dec_act; }
        else if (t & 1) {
            int b2 = (t + 1) >> 1; nclass = b2;
            dec = dec_block + (size_t)(b2 - 1) * (NB - 1) * H;
        } else {
            int b2 = t >> 1; nclass = 4;
            dec = dec_act + (size_t)b2 * 4 * H;
        }
        if (w == 0) {
            for (int cl = 0; cl < nclass; ++cl) {
                float v = (lane < 8)
                              ? dec[(size_t)cl * H + bid * 8 + lane] * hsl[lane]
                              : 0.f;
                v += __shfl_xor(v, 1, 64);
                v += __shfl_xor(v, 2, 64);
                v += __shfl_xor(v, 4, 64);
                if (lane == 0) st_agent(pbuf + cl * 256 + bid, v);
            }
        }

        grid_barrier_nf(arr, bid, t + 1, tid);

        // wide coherent h gather -> LDS
        {
            float4 hv = ld_agent_f4(hbuf + tid * 4);
            ((float4*)h_s)[tid] = hv;
        }
        // reduce partials -> logits
        for (int cl = w; cl < nclass; cl += 8) {
            float4 pv = ld_agent_f4(pbuf + cl * 256 + lane * 4);
            float s = pv.x + pv.y + pv.z + pv.w;
#pragma unroll
            for (int off = 32; off > 0; off >>= 1)
                s += __shfl_xor(s, off, 64);
            if (lane == 0) logits_s[cl] = s;
        }
        __syncthreads();
        {
            float best = logits_s[0]; int bi = 0;
            for (int cl = 1; cl < nclass; ++cl)
                if (logits_s[cl] > best) { best = logits_s[cl]; bi = cl; }
            idx = bi;
        }
        if (t < NSTEP - 1) {
            if ((t & 1) == 0) emb = (t >> 1) * 4 + idx;
            else emb = 44 + ((t - 1) >> 1) * 11 + idx;
        }
        __syncthreads();
    }

    if (lane == 0) st_agent(c_arr + bid * 8 + w, c_reg);
    grid_barrier_nf(arr, bid, NSTEP + 1, tid);

    if (bid == 0) { out[tid] = (float)idx; out[tid + NTHR] = (float)idx; }
    float4 hv4 = ((const float4*)h_s)[tid];
    float4 cv4 = ld_agent_f4(c_arr + tid * 4);
    float4* oh = (float4*)(out + B);
    float4* oc = (float4*)(out + B + (size_t)B * H);
#pragma unroll
    for (int r = 0; r < 4; ++r) {
        int orow = bid * 4 + r;
        oh[(size_t)orow * (H / 4) + tid] = hv4;
        oc[(size_t)orow * (H / 4) + tid] = cv4;
    }
}

// ---------------- fp32 fallback path (tiny ws) — R1-proven ---------------
__global__ __launch_bounds__(256) void zero_c_kernel(float* __restrict__ cv) {
    int j = blockIdx.x * 256 + threadIdx.x;
    if (j < H) cv[j] = 0.f;
}
__global__ __launch_bounds__(256) void bias_gates_kernel(
    const float* __restrict__ bih, const float* __restrict__ bhh,
    float* __restrict__ gates) {
    int j = blockIdx.x * 256 + threadIdx.x;
    if (j < 4 * H) gates[j] = bih[j] + bhh[j];
}
__global__ __launch_bounds__(256) void gates_kernel(
    const float* __restrict__ Wih, const float* __restrict__ Whh,
    const float* __restrict__ bih, const float* __restrict__ bhh,
    const float* __restrict__ x, const float* __restrict__ h,
    float* __restrict__ gates) {
    const int wave = threadIdx.x >> 6;
    const int lane = threadIdx.x & 63;
    const int row = blockIdx.x * 4 + wave;
    const float4* Wi4 = (const float4*)(Wih + (size_t)row * H);
    const float4* Wh4 = (const float4*)(Whh + (size_t)row * H);
    const float4* x4 = (const float4*)x;
    const float4* h4 = (const float4*)h;
    float acc = 0.f;
#pragma unroll
    for (int k = 0; k < H / 256; ++k) {
        int j = k * 64 + lane;
        float4 wv = Wi4[j]; float4 v = x4[j];
        acc += wv.x * v.x + wv.y * v.y + wv.z * v.z + wv.w * v.w;
    }
#pragma unroll
    for (int k = 0; k < H / 256; ++k) {
        int j = k * 64 + lane;
        float4 wv = Wh4[j]; float4 v = h4[j];
        acc += wv.x * v.x + wv.y * v.y + wv.z * v.z + wv.w * v.w;
    }
    for (int off = 32; off > 0; off >>= 1) acc += __shfl_down(acc, off, 64);
    if (lane == 0) gates[row] = acc + bih[row] + bhh[row];
}
__global__ __launch_bounds__(256) void update_kernel(
    const float* __restrict__ gates,
    float* __restrict__ xv, float* __restrict__ hv, float* __restrict__ cv,
    const float* __restrict__ dec, int nclass,
    const float* __restrict__ enc, int* __restrict__ idx_ptr) {
    const int t = threadIdx.x;
    __shared__ float red[256];
    __shared__ float logits[16];
    __shared__ int sidx;
    float hl[8];
#pragma unroll
    for (int k = 0; k < 8; ++k) {
        int j = k * 256 + t;
        float si = sigm(gates[j]);
        float sf = sigm(gates[H + j]);
        float so = sigm(gates[3 * H + j]);
        float tg = tanhf(gates[2 * H + j]);
        float c2 = sf * cv[j] + si * tg;
        float h2 = so * tanhf(c2);
        cv[j] = c2; hv[j] = h2; hl[k] = h2;
    }
    __syncthreads();
    for (int cl = 0; cl < nclass; ++cl) {
        const float* dr = dec + (size_t)cl * H;
        float p = 0.f;
#pragma unroll
        for (int k = 0; k < 8; ++k) p += hl[k] * dr[k * 256 + t];
        red[t] = p;
        __syncthreads();
        for (int s = 128; s > 0; s >>= 1) {
            if (t < s) red[t] += red[t + s];
            __syncthreads();
        }
        if (t == 0) logits[cl] = red[0];
        __syncthreads();
    }
    if (t == 0) {
        float best = logits[0]; int bi = 0;
        for (int cl = 1; cl < nclass; ++cl)
            if (logits[cl] > best) { best = logits[cl]; bi = cl; }
        sidx = bi; *idx_ptr = bi;
    }
    __syncthreads();
    if (enc != nullptr) {
        const float* er = enc + (size_t)sidx * H;
#pragma unroll
        for (int k = 0; k < 8; ++k) xv[k * 256 + t] = er[k * 256 + t];
    }
}
__global__ __launch_bounds__(256) void final_kernel(
    const float* __restrict__ hv, const float* __restrict__ cv,
    const int* __restrict__ idx_ptr, float* __restrict__ out) {
    const int tid = blockIdx.x * 256 + threadIdx.x;
    const int col = tid & (H / 4 - 1);
    ((float4*)(out + B))[tid] = ((const float4*)hv)[col];
    ((float4*)(out + B + (size_t)B * H))[tid] = ((const float4*)cv)[col];
    if (tid < B) out[tid] = (float)(*idx_ptr);
}

extern "C" void kernel_launch(void* const* d_in, const int* in_sizes, int n_in,
                              void* d_out, int out_size, void* d_ws, size_t ws_size,
                              hipStream_t stream) {
    const float* W_ih      = (const float*)d_in[1];
    const float* W_hh      = (const float*)d_in[2];
    const float* b_ih      = (const float*)d_in[3];
    const float* b_hh      = (const float*)d_in[4];
    const float* enc_act   = (const float*)d_in[5];
    const float* enc_block = (const float*)d_in[6];
    const float* dec_act   = (const float*)d_in[7];
    const float* dec_block = (const float*)d_in[8];
    float* out = (float*)d_out;
    char* ws = (char*)d_ws;

    if (ws_size >= WS_NEED) {
        uint4*    Whh16 = (uint4*)(ws + OFF_WHH);
        float*    shh   = (float*)(ws + OFF_SHH);
        uint32_t* E     = (uint32_t*)(ws + OFF_E);
        float*    PRE   = (float*)(ws + OFF_PRE);
        float*    PREP  = (float*)(ws + OFF_PREP);
        float*    h0    = (float*)(ws + OFF_H0);
        float*    h1    = (float*)(ws + OFF_H1);
        float*    c_arr = (float*)(ws + OFF_C);
        float*    p0    = (float*)(ws + OFF_P0);
        float*    p1    = (float*)(ws + OFF_P1);
        int*      arr   = (int*)(ws + OFF_ARR);

        build_e_kernel<<<NEMB, 256, 0, stream>>>(enc_act, enc_block, E);
        pre_mfma_kernel<<<1024, 128, 0, stream>>>(W_ih, (const uint16_t*)E,
                                                  PREP);
        pre_reduce_kernel<<<1408, 256, 0, stream>>>(PREP, b_ih, b_hh, PRE);
        quant_i16_kernel<<<2048, 256, 0, stream>>>(W_hh, Whh16, shh);
        hipMemsetAsync(arr, 0, 1024, stream);
        lstm_persist<<<NBLK, NTHR, 0, stream>>>(
            Whh16, shh, PRE, dec_act, dec_block,
            h0, h1, c_arr, p0, p1, arr, out);
        return;
    }

    // fallback: fp32 multi-kernel path
    float* state = (float*)d_ws;
    float* xv = state;
    float* hv = state + H;
    float* cv = state + 2 * H;
    float* gates = state + 3 * H;
    int* idxp = (int*)(state + 7 * H);

    zero_c_kernel<<<8, 256, 0, stream>>>(cv);
    bias_gates_kernel<<<32, 256, 0, stream>>>(b_ih, b_hh, gates);
    update_kernel<<<1, 256, 0, stream>>>(gates, xv, hv, cv, dec_act, 4,
                                         enc_act, idxp);
    for (int bid = 1; bid < NB; ++bid) {
        gates_kernel<<<2048, 256, 0, stream>>>(W_ih, W_hh, b_ih, b_hh,
                                               xv, hv, gates);
        update_kernel<<<1, 256, 0, stream>>>(
            gates, xv, hv, cv,
            dec_block + (size_t)(bid - 1) * (NB - 1) * H, bid,
            enc_block + (size_t)(bid - 1) * (NB - 1) * H, idxp);
        gates_kernel<<<2048, 256, 0, stream>>>(W_ih, W_hh, b_ih, b_hh,
                                               xv, hv, gates);
        update_kernel<<<1, 256, 0, stream>>>(
            gates, xv, hv, cv,
            dec_act + (size_t)bid * 4 * H, 4,
            (bid < NB - 1) ? (enc_act + (size_t)bid * 4 * H) : nullptr, idxp);
    }
    final_kernel<<<2048, 256, 0, stream>>>(hv, cv, idxp, out);
}